// Round 10
// baseline (359.286 us; speedup 1.0000x reference)
//
#include <hip/hip_runtime.h>

#define BATCH 2
#define SQL   4096
#define CDIM  1280
#define SKV   77
#define CENC  2048
#define NH    20
#define DHD   64
#define KVP   96        // kv padded to 3*32 for MFMA K
#define SCALE 0.125f
#define TAUC  0.1f
#define BETAC 0.5f

typedef __attribute__((ext_vector_type(4))) float  f32x4;
typedef __attribute__((ext_vector_type(8))) __bf16 bf16x8;

typedef __attribute__((address_space(1))) unsigned int gu32;
typedef __attribute__((address_space(3))) unsigned int lu32;

__device__ __forceinline__ unsigned short f2b(float x) {
  union { float f; unsigned u; } a; a.f = x;
  unsigned r = a.u + 0x7FFFu + ((a.u >> 16) & 1u);
  return (unsigned short)(r >> 16);
}

__device__ __forceinline__ f32x4 mfma16(bf16x8 a, bf16x8 b, f32x4 c) {
  return __builtin_amdgcn_mfma_f32_16x16x32_bf16(a, b, c, 0, 0, 0);
}

// ---------------- merged prep: X->bf16, enc pad->bf16, 4 weight transposes ----------------
// grid: [0,2048) X conv; [2048,2560) enc pad; [2560,2960) Wq; [2960,3360) Wo;
//       [3360,4000) Wk; [4000,4640) Wv.  Transposes: 64x64 tiles, ushort4 stores.
__global__ __launch_bounds__(256) void prep_trans_kernel(
    const float* __restrict__ X, unsigned short* __restrict__ Xb,
    const float* __restrict__ enc, unsigned short* __restrict__ encb,
    const float* __restrict__ Wq, unsigned short* __restrict__ WqT,
    const float* __restrict__ Wo, unsigned short* __restrict__ WoT,
    const float* __restrict__ Wk, unsigned short* __restrict__ WkT,
    const float* __restrict__ Wv, unsigned short* __restrict__ WvT) {
  __shared__ float tile[64][65];
  const int bid = blockIdx.x;
  const int t = threadIdx.x;
  if (bid < 2048) {
    const int n4 = (BATCH * SQL * CDIM) / 4;
    for (int i = bid * 256 + t; i < n4; i += 2048 * 256) {
      const float4 v = ((const float4*)X)[i];
      ushort4 o;
      o.x = f2b(v.x); o.y = f2b(v.y); o.z = f2b(v.z); o.w = f2b(v.w);
      ((ushort4*)Xb)[i] = o;
    }
    return;
  }
  if (bid < 2560) {
    const int i = (bid - 2048) * 256 + t;  // 131072 f4 groups
    float4 v; v.x = 0.f; v.y = 0.f; v.z = 0.f; v.w = 0.f;
    if (i < (BATCH * SKV) * (CENC / 4)) v = ((const float4*)enc)[i];
    ushort4 o;
    o.x = f2b(v.x); o.y = f2b(v.y); o.z = f2b(v.z); o.w = f2b(v.w);
    ((ushort4*)encb)[i] = o;
    return;
  }
  const float* in;
  unsigned short* out;
  int R, by, bx;
  if (bid < 2960)      { const int tt = bid - 2560; in = Wq; out = WqT; R = CDIM; by = tt / 20; bx = tt % 20; }
  else if (bid < 3360) { const int tt = bid - 2960; in = Wo; out = WoT; R = CDIM; by = tt / 20; bx = tt % 20; }
  else if (bid < 4000) { const int tt = bid - 3360; in = Wk; out = WkT; R = CENC; by = tt / 20; bx = tt % 20; }
  else                 { const int tt = bid - 4000; in = Wv; out = WvT; R = CENC; by = tt / 20; bx = tt % 20; }
  const int by64 = by * 64, bx64 = bx * 64;
  const int tx = t & 63;
  const int ty = t >> 6;            // 0..3
#pragma unroll
  for (int r = 0; r < 16; ++r) {
    const int row = ty + r * 4;     // 0..63
    tile[row][tx] = in[(size_t)(by64 + row) * CDIM + bx64 + tx];
  }
  __syncthreads();
  const int c4 = t & 15;            // 4-col group within 64
  const int j0 = t >> 4;            // 0..15
#pragma unroll
  for (int k = 0; k < 4; ++k) {
    const int j = j0 + k * 16;      // output row within tile (input col)
    ushort4 w;
    w.x = f2b(tile[c4 * 4 + 0][j]);
    w.y = f2b(tile[c4 * 4 + 1][j]);
    w.z = f2b(tile[c4 * 4 + 2][j]);
    w.w = f2b(tile[c4 * 4 + 3][j]);
    *(ushort4*)&out[(size_t)(bx64 + j) * R + by64 + c4 * 4] = w;
  }
}

// ---------------- fused Q-proj GEMM + attention ----------------
// A = Xb [8192][1280] bf16, BT = WqT [1280][1280]; per block: 128 q-rows x 2 heads.
// LDS = exactly 32 KB. Epilogue scratch: per-wave 4096-short quadrant
// (waves 0-1 in ldsA, 2-3 in ldsB): Q-rg tile at [0,1024), P at [2048,3712).
__global__ __launch_bounds__(256, 4) void gemm_q_attn(
    const unsigned short* __restrict__ A, const unsigned short* __restrict__ BT,
    const unsigned short* __restrict__ kp, const unsigned short* __restrict__ vtp,
    unsigned short* __restrict__ ao) {
  __shared__ __align__(16) unsigned short ldsA[128 * 64];
  __shared__ __align__(16) unsigned short ldsB[128 * 64];
  const int t = threadIdx.x;
  const int lane = t & 63;
  const int wave = t >> 6;
  const int lin = blockIdx.x;
  const int nwg = gridDim.x;                 // 640, %8==0
  const int q8 = nwg >> 3;
  const int xcd = lin & 7, sub = lin >> 3;
  const int wg = xcd * q8 + sub;             // bijective (nwg%8==0)
  const int ntile = CDIM >> 7;               // 10
  const int m0 = (wg / ntile) * 128;
  const int n0 = (wg % ntile) * 128;
  const int wr0 = (wave >> 1) * 64;
  const int wc0 = (wave & 1) * 64;
  const int lr = lane & 15;
  const int kg = lane >> 4;
  const int srow = t >> 3;
  const int sslot = t & 7;

  f32x4 acc[4][4] = {};

  for (int k0 = 0; k0 < CDIM; k0 += 64) {
#pragma unroll
    for (int c = 0; c < 4; ++c) {
      const int row = c * 32 + srow;
      const int slot = sslot ^ (row & 7);   // pre-swizzled global source
      const unsigned short* ga = A  + (size_t)(m0 + row) * CDIM + k0 + slot * 8;
      const unsigned short* gb = BT + (size_t)(n0 + row) * CDIM + k0 + slot * 8;
      __builtin_amdgcn_global_load_lds((gu32*)ga, (lu32*)&ldsA[c * 2048 + wave * 512], 16, 0, 0);
      __builtin_amdgcn_global_load_lds((gu32*)gb, (lu32*)&ldsB[c * 2048 + wave * 512], 16, 0, 0);
    }
    __syncthreads();
#pragma unroll
    for (int s = 0; s < 2; ++s) {
      const int slot = s * 4 + kg;
      bf16x8 af[4], bf[4];
#pragma unroll
      for (int i = 0; i < 4; ++i) {
        const int r = wr0 + i * 16 + lr;
        af[i] = *(const bf16x8*)&ldsA[r * 64 + (slot ^ (r & 7)) * 8];
        const int n = wc0 + i * 16 + lr;
        bf[i] = *(const bf16x8*)&ldsB[n * 64 + (slot ^ (n & 7)) * 8];
      }
#pragma unroll
      for (int i = 0; i < 4; ++i)
#pragma unroll
        for (int j = 0; j < 4; ++j)
          acc[i][j] = mfma16(af[i], bf[j], acc[i][j]);
    }
    __syncthreads();
  }
  // after this barrier all LDS reads are drained; quadrants become wave-private.

  unsigned short* ldsW = (wave < 2) ? (ldsA + wave * 4096) : (ldsB + (wave - 2) * 4096);
  unsigned short* Pw = ldsW + 2048;               // [2048,3712) of the quadrant

  const int h = n0 / 64 + (wave & 1);             // global head 0..19
  const int b = m0 >> 12;                          // SQL = 4096
  const int bh = b * NH + h;

#pragma unroll 1
  for (int rg = 0; rg < 4; ++rg) {
    // ---- stage this rg's 16x64 q rows (bf16, XOR-8 swizzle) into [0,1024) ----
#pragma unroll
    for (int j = 0; j < 4; ++j)
#pragma unroll
      for (int r = 0; r < 4; ++r) {
        const int row16 = kg * 4 + r;             // 0..15
        const int d = j * 16 + lr;                // 0..63
        const int slot = (d >> 3) ^ (row16 & 7);
        ldsW[row16 * 64 + slot * 8 + (d & 7)] = f2b(acc[rg][j][r]);
      }
    // q fragments (row16 = lr); rg*16 ≡ 0 mod 8 so swizzle matches R7's
    bf16x8 qa[2];
#pragma unroll
    for (int s = 0; s < 2; ++s)
      qa[s] = *(const bf16x8*)&ldsW[lr * 64 + (((s * 4 + kg) ^ (lr & 7)) * 8)];

    // QK^T
    f32x4 sc[5];
    __builtin_amdgcn_s_setprio(1);
#pragma unroll
    for (int n = 0; n < 5; ++n) {
      f32x4 a = {};
#pragma unroll
      for (int s = 0; s < 2; ++s) {
        bf16x8 kf = *(const bf16x8*)&kp[((size_t)bh * KVP + n * 16 + lr) * DHD + s * 32 + kg * 8];
        a = mfma16(qa[s], kf, a);
      }
      sc[n] = a;
    }
    __builtin_amdgcn_s_setprio(0);

    // max-free softmax; 1/sum folded into PV output (same lane/row)
    float pv[5][4];
    float inv[4];
#pragma unroll
    for (int reg = 0; reg < 4; ++reg) {
      float sum = 0.f;
#pragma unroll
      for (int n = 0; n < 4; ++n) {        // kv = n*16+lr <= 63 < 77: no mask
        const float p = __expf(sc[n][reg] * SCALE);
        pv[n][reg] = p;
        sum += p;
      }
      {                                     // n=4: kv = 64+lr, valid iff lr<13
        const float p = (lr < 13) ? __expf(sc[4][reg] * SCALE) : 0.f;
        pv[4][reg] = p;
        sum += p;
      }
      sum += __shfl_xor(sum, 1);
      sum += __shfl_xor(sum, 2);
      sum += __shfl_xor(sum, 4);
      sum += __shfl_xor(sum, 8);
      inv[reg] = 1.f / sum;
    }

    // P -> LDS bf16 (unnormalized), zero pad cols 80..95
#pragma unroll
    for (int reg = 0; reg < 4; ++reg) {
      const int row = kg * 4 + reg;
#pragma unroll
      for (int n = 0; n < 5; ++n)
        Pw[row * 104 + n * 16 + lr] = f2b(pv[n][reg]);
      Pw[row * 104 + 80 + lr] = 0;
    }

    // PV
    bf16x8 pa[3];
#pragma unroll
    for (int s = 0; s < 3; ++s)
      pa[s] = *(const bf16x8*)&Pw[lr * 104 + s * 32 + kg * 8];
    __builtin_amdgcn_s_setprio(1);
#pragma unroll
    for (int dsub = 0; dsub < 4; ++dsub) {
      f32x4 o = {};
#pragma unroll
      for (int s = 0; s < 3; ++s) {
        bf16x8 vfg = *(const bf16x8*)&vtp[((size_t)bh * DHD + dsub * 16 + lr) * KVP + s * 32 + kg * 8];
        o = mfma16(pa[s], vfg, o);
      }
#pragma unroll
      for (int reg = 0; reg < 4; ++reg)
        ao[(size_t)(m0 + wr0 + rg * 16 + kg * 4 + reg) * CDIM + h * DHD + dsub * 16 + lr] =
            f2b(o[reg] * inv[reg]);
    }
    __builtin_amdgcn_s_setprio(0);
  }
}

// ---------------- O-proj GEMM: C[M][N] = A[M][K] * BT[N][K]^T, f32 out + bias
__global__ __launch_bounds__(256, 4) void gemm_bt(
    const unsigned short* __restrict__ A, const unsigned short* __restrict__ BT,
    float* __restrict__ Cf, const float* __restrict__ bias, int M, int N, int K) {
  __shared__ __align__(16) unsigned short ldsA[128 * 64];
  __shared__ __align__(16) unsigned short ldsB[128 * 64];
  const int t = threadIdx.x;
  const int lane = t & 63;
  const int wave = t >> 6;
  const int lin = blockIdx.x;
  const int nwg = gridDim.x;
  const int q8 = nwg >> 3, r8 = nwg & 7;
  const int xcd = lin & 7, sub = lin >> 3;
  const int wg = (xcd < r8 ? xcd * (q8 + 1) : r8 * (q8 + 1) + (xcd - r8) * q8) + sub;
  const int ntile = N >> 7;
  const int m0 = (wg / ntile) * 128;
  const int n0 = (wg % ntile) * 128;
  const int wr0 = (wave >> 1) * 64;
  const int wc0 = (wave & 1) * 64;
  const int lr = lane & 15;
  const int kg = lane >> 4;
  const int srow = t >> 3;
  const int sslot = t & 7;

  f32x4 acc[4][4] = {};

  for (int k0 = 0; k0 < K; k0 += 64) {
#pragma unroll
    for (int c = 0; c < 4; ++c) {
      const int row = c * 32 + srow;
      const int slot = sslot ^ (row & 7);
      const unsigned short* ga = A  + (size_t)(m0 + row) * K + k0 + slot * 8;
      const unsigned short* gb = BT + (size_t)(n0 + row) * K + k0 + slot * 8;
      __builtin_amdgcn_global_load_lds((gu32*)ga, (lu32*)&ldsA[c * 2048 + wave * 512], 16, 0, 0);
      __builtin_amdgcn_global_load_lds((gu32*)gb, (lu32*)&ldsB[c * 2048 + wave * 512], 16, 0, 0);
    }
    __syncthreads();
#pragma unroll
    for (int s = 0; s < 2; ++s) {
      const int slot = s * 4 + kg;
      bf16x8 af[4], bf[4];
#pragma unroll
      for (int i = 0; i < 4; ++i) {
        const int r = wr0 + i * 16 + lr;
        af[i] = *(const bf16x8*)&ldsA[r * 64 + (slot ^ (r & 7)) * 8];
        const int n = wc0 + i * 16 + lr;
        bf[i] = *(const bf16x8*)&ldsB[n * 64 + (slot ^ (n & 7)) * 8];
      }
#pragma unroll
      for (int i = 0; i < 4; ++i)
#pragma unroll
        for (int j = 0; j < 4; ++j)
          acc[i][j] = mfma16(af[i], bf[j], acc[i][j]);
    }
    __syncthreads();
  }

#pragma unroll
  for (int j = 0; j < 4; ++j) {
    const int col = n0 + wc0 + j * 16 + lr;
    const float bj = bias[col];
#pragma unroll
    for (int i = 0; i < 4; ++i)
#pragma unroll
      for (int r = 0; r < 4; ++r) {
        const int row = m0 + wr0 + i * 16 + kg * 4 + r;
        Cf[(size_t)row * N + col] = acc[i][j][r] + bj;
      }
  }
}

// ---------------- fused K/V projection, split-K x4 -> f32 partials pk[z][256][1280]
__global__ __launch_bounds__(256) void gemm_kv(
    const unsigned short* __restrict__ A, const unsigned short* __restrict__ BTk,
    const unsigned short* __restrict__ BTv, float* __restrict__ pk) {
  __shared__ __align__(16) unsigned short ldsA[128 * 64];
  __shared__ __align__(16) unsigned short ldsB[128 * 64];
  const int t = threadIdx.x;
  const int lane = t & 63;
  const int wave = t >> 6;
  const int z = blockIdx.z;            // out*4 + ks
  const unsigned short* BT = (z >> 2) ? BTv : BTk;
  const int ks = z & 3;
  const int m0 = blockIdx.x * 128;
  const int n0 = blockIdx.y * 128;
  float* C = pk + (size_t)z * 256 * CDIM;
  const int wr0 = (wave >> 1) * 64;
  const int wc0 = (wave & 1) * 64;
  const int lr = lane & 15;
  const int kg = lane >> 4;
  const int srow = t >> 3;
  const int sslot = t & 7;

  f32x4 acc[4][4] = {};

  for (int k0 = ks * 512; k0 < (ks + 1) * 512; k0 += 64) {
#pragma unroll
    for (int c = 0; c < 4; ++c) {
      const int row = c * 32 + srow;
      const int slot = sslot ^ (row & 7);
      const unsigned short* ga = A  + (size_t)(m0 + row) * CENC + k0 + slot * 8;
      const unsigned short* gb = BT + (size_t)(n0 + row) * CENC + k0 + slot * 8;
      __builtin_amdgcn_global_load_lds((gu32*)ga, (lu32*)&ldsA[c * 2048 + wave * 512], 16, 0, 0);
      __builtin_amdgcn_global_load_lds((gu32*)gb, (lu32*)&ldsB[c * 2048 + wave * 512], 16, 0, 0);
    }
    __syncthreads();
#pragma unroll
    for (int s = 0; s < 2; ++s) {
      const int slot = s * 4 + kg;
      bf16x8 af[4], bf[4];
#pragma unroll
      for (int i = 0; i < 4; ++i) {
        const int r = wr0 + i * 16 + lr;
        af[i] = *(const bf16x8*)&ldsA[r * 64 + (slot ^ (r & 7)) * 8];
        const int n = wc0 + i * 16 + lr;
        bf[i] = *(const bf16x8*)&ldsB[n * 64 + (slot ^ (n & 7)) * 8];
      }
#pragma unroll
      for (int i = 0; i < 4; ++i)
#pragma unroll
        for (int j = 0; j < 4; ++j)
          acc[i][j] = mfma16(af[i], bf[j], acc[i][j]);
    }
    __syncthreads();
  }

#pragma unroll
  for (int j = 0; j < 4; ++j) {
    const int col = n0 + wc0 + j * 16 + lr;
#pragma unroll
    for (int i = 0; i < 4; ++i)
#pragma unroll
      for (int r = 0; r < 4; ++r) {
        const int row = m0 + wr0 + i * 16 + kg * 4 + r;
        C[(size_t)row * CDIM + col] = acc[i][j][r];
      }
  }
}

// ---------------- CORA erase + split-K reduce + K pack + zero-padding (grid BATCH*96)
__global__ __launch_bounds__(256) void cora_kernel(
    const float* __restrict__ pk, const float* __restrict__ Bp,
    const float* __restrict__ uh, const float* __restrict__ ah,
    unsigned short* __restrict__ vtp, unsigned short* __restrict__ kp) {
  const int bs = blockIdx.x;
  const int b = bs / KVP;
  const int s = bs % KVP;
  const int t = threadIdx.x;
  if (s >= SKV) {   // pad rows: zero vtp and kp
#pragma unroll
    for (int e = 0; e < 5; ++e) {
      const int hh = t + e * 256;
      const int head = hh >> 6, d = hh & 63;
      vtp[(((size_t)b * NH + head) * DHD + d) * KVP + s] = 0;
      kp[(((size_t)b * NH + head) * KVP + s) * DHD + d] = 0;
    }
    return;
  }
  const int rbs = b * SKV + s;
  const int lane = t & 63;
  const int wave = t >> 6;
  const int STR = 256 * CDIM;
  __shared__ float red1[4][4];
  __shared__ float red2[4][2];
  float vv[5], vfr[5], vpr[5];
  float c0 = 0.f, c1 = 0.f, c2 = 0.f, c3 = 0.f;
#pragma unroll
  for (int e = 0; e < 5; ++e) {
    const int hh = t + e * 256;
    const float* base = pk + (size_t)rbs * CDIM + hh;
    const float kv_ = base[0] + base[STR] + base[2 * STR] + base[3 * STR];
    const int head = hh >> 6, d = hh & 63;
    kp[(((size_t)b * NH + head) * KVP + s) * DHD + d] = f2b(kv_);
    const float x = base[4 * STR] + base[5 * STR] + base[6 * STR] + base[7 * STR];
    vv[e] = x;
    const float* bp = Bp + ((size_t)s * CDIM + hh) * 4;
    c0 += x * bp[0]; c1 += x * bp[1]; c2 += x * bp[2]; c3 += x * bp[3];
  }
#pragma unroll
  for (int d = 32; d >= 1; d >>= 1) {
    c0 += __shfl_xor(c0, d); c1 += __shfl_xor(c1, d);
    c2 += __shfl_xor(c2, d); c3 += __shfl_xor(c3, d);
  }
  if (lane == 0) { red1[wave][0] = c0; red1[wave][1] = c1; red1[wave][2] = c2; red1[wave][3] = c3; }
  __syncthreads();
  c0 = red1[0][0] + red1[1][0] + red1[2][0] + red1[3][0];
  c1 = red1[0][1] + red1[1][1] + red1[2][1] + red1[3][1];
  c2 = red1[0][2] + red1[1][2] + red1[2][2] + red1[3][2];
  c3 = red1[0][3] + red1[1][3] + red1[2][3] + red1[3][3];
  float tp = 0.f, np = 0.f;
#pragma unroll
  for (int e = 0; e < 5; ++e) {
    const int hh = t + e * 256;
    const float* bp = Bp + ((size_t)s * CDIM + hh) * 4;
    const float vp = c0 * bp[0] + c1 * bp[1] + c2 * bp[2] + c3 * bp[3];
    const float fr = vv[e] - vp;
    vpr[e] = vp; vfr[e] = fr;
    tp += fr * uh[(size_t)s * CDIM + hh];
    np += fr * fr;
  }
#pragma unroll
  for (int d = 32; d >= 1; d >>= 1) { tp += __shfl_xor(tp, d); np += __shfl_xor(np, d); }
  if (lane == 0) { red2[wave][0] = tp; red2[wave][1] = np; }
  __syncthreads();
  const float tt = red2[0][0] + red2[1][0] + red2[2][0] + red2[3][0];
  const float nn = red2[0][1] + red2[1][1] + red2[2][1] + red2[3][1];
  const float denom = sqrtf(nn) + 1e-8f;
  const bool gate = fabsf(tt) >= TAUC * denom;   // frac >= TAU
#pragma unroll
  for (int e = 0; e < 5; ++e) {
    const int hh = t + e * 256;
    float o = vfr[e];
    if (gate) o = o - tt * uh[(size_t)s * CDIM + hh] + BETAC * tt * ah[(size_t)s * CDIM + hh];
    o += vpr[e];
    const int head = hh >> 6, d = hh & 63;
    vtp[(((size_t)b * NH + head) * DHD + d) * KVP + s] = f2b(o);
  }
}

// ---------------- launch ----------------

extern "C" void kernel_launch(void* const* d_in, const int* in_sizes, int n_in,
                              void* d_out, int out_size, void* d_ws, size_t ws_size,
                              hipStream_t stream) {
  const float* X   = (const float*)d_in[0];
  const float* enc = (const float*)d_in[1];
  const float* Wq  = (const float*)d_in[2];
  const float* Wk  = (const float*)d_in[3];
  const float* Wv  = (const float*)d_in[4];
  const float* Wo  = (const float*)d_in[5];
  const float* bo  = (const float*)d_in[6];
  const float* Bp  = (const float*)d_in[7];
  const float* uh  = (const float*)d_in[8];
  const float* ah  = (const float*)d_in[9];
  float* out = (float*)d_out;

  char* w = (char*)d_ws;
  unsigned short* Xb   = (unsigned short*)(w);                // 8192*1280 bf16
  unsigned short* attn = (unsigned short*)(w + 20971520);     // 8192*1280 bf16 (attn out)
  float*          pk   = (float*)         (w + 20971520);     // alias: 8*256*1280 f32, dead before attn written
  unsigned short* WqT  = (unsigned short*)(w + 41943040);     // 1280*1280 bf16
  unsigned short* WoT  = (unsigned short*)(w + 45219840);     // 1280*1280 bf16
  unsigned short* WkT  = (unsigned short*)(w + 48496640);     // 1280*2048 bf16
  unsigned short* WvT  = (unsigned short*)(w + 53739520);     // 1280*2048 bf16
  unsigned short* encb = (unsigned short*)(w + 58982400);     // 256*2048 bf16
  unsigned short* kp   = (unsigned short*)(w + 61997056);     // 2*20*96*64 bf16
  unsigned short* vtp  = (unsigned short*)(w + 62488576);     // 2*20*64*96 bf16
  // total 62,980,096 B

  prep_trans_kernel<<<4640, 256, 0, stream>>>(X, Xb, enc, encb,
      Wq, WqT, Wo, WoT, Wk, WkT, Wv, WvT);

  gemm_kv<<<dim3(2, 10, 8), 256, 0, stream>>>(encb, WkT, WvT, pk);
  cora_kernel<<<BATCH * KVP, 256, 0, stream>>>(pk, Bp, uh, ah, vtp, kp);

  gemm_q_attn<<<640, 256, 0, stream>>>(Xb, WqT, kp, vtp, attn);
  gemm_bt<<<640, 256, 0, stream>>>(attn, WoT, out, bo, BATCH * SQL, CDIM, CDIM);
}

// Round 11
// 117.516 us; speedup vs baseline: 3.0573x; 3.0573x over previous
//
#include <hip/hip_runtime.h>

#define BATCH 2
#define SQL   4096
#define CDIM  1280
#define SKV   77
#define CENC  2048
#define NH    20
#define DHD   64
#define KVP   96        // kv padded to 3*32 for MFMA K
#define SCALE 0.125f
#define TAUC  0.1f
#define BETAC 0.5f

typedef __attribute__((ext_vector_type(4))) float  f32x4;
typedef __attribute__((ext_vector_type(8))) __bf16 bf16x8;

typedef __attribute__((address_space(1))) unsigned int gu32;
typedef __attribute__((address_space(3))) unsigned int lu32;

__device__ __forceinline__ unsigned short f2b(float x) {
  union { float f; unsigned u; } a; a.f = x;
  unsigned r = a.u + 0x7FFFu + ((a.u >> 16) & 1u);
  return (unsigned short)(r >> 16);
}

__device__ __forceinline__ f32x4 mfma16(bf16x8 a, bf16x8 b, f32x4 c) {
  return __builtin_amdgcn_mfma_f32_16x16x32_bf16(a, b, c, 0, 0, 0);
}

// ---------------- merged prep: X->bf16, enc pad->bf16, 4 weight transposes ----------------
// grid: [0,2048) X conv; [2048,2560) enc pad; [2560,2960) Wq; [2960,3360) Wo;
//       [3360,4000) Wk; [4000,4640) Wv.  Transposes: 64x64 tiles, ushort4 stores.
__global__ __launch_bounds__(256) void prep_trans_kernel(
    const float* __restrict__ X, unsigned short* __restrict__ Xb,
    const float* __restrict__ enc, unsigned short* __restrict__ encb,
    const float* __restrict__ Wq, unsigned short* __restrict__ WqT,
    const float* __restrict__ Wo, unsigned short* __restrict__ WoT,
    const float* __restrict__ Wk, unsigned short* __restrict__ WkT,
    const float* __restrict__ Wv, unsigned short* __restrict__ WvT) {
  __shared__ float tile[64][65];
  const int bid = blockIdx.x;
  const int t = threadIdx.x;
  if (bid < 2048) {
    const int n4 = (BATCH * SQL * CDIM) / 4;
    for (int i = bid * 256 + t; i < n4; i += 2048 * 256) {
      const float4 v = ((const float4*)X)[i];
      ushort4 o;
      o.x = f2b(v.x); o.y = f2b(v.y); o.z = f2b(v.z); o.w = f2b(v.w);
      ((ushort4*)Xb)[i] = o;
    }
    return;
  }
  if (bid < 2560) {
    const int i = (bid - 2048) * 256 + t;  // 131072 f4 groups
    float4 v; v.x = 0.f; v.y = 0.f; v.z = 0.f; v.w = 0.f;
    if (i < (BATCH * SKV) * (CENC / 4)) v = ((const float4*)enc)[i];
    ushort4 o;
    o.x = f2b(v.x); o.y = f2b(v.y); o.z = f2b(v.z); o.w = f2b(v.w);
    ((ushort4*)encb)[i] = o;
    return;
  }
  const float* in;
  unsigned short* out;
  int R, by, bx;
  if (bid < 2960)      { const int tt = bid - 2560; in = Wq; out = WqT; R = CDIM; by = tt / 20; bx = tt % 20; }
  else if (bid < 3360) { const int tt = bid - 2960; in = Wo; out = WoT; R = CDIM; by = tt / 20; bx = tt % 20; }
  else if (bid < 4000) { const int tt = bid - 3360; in = Wk; out = WkT; R = CENC; by = tt / 20; bx = tt % 20; }
  else                 { const int tt = bid - 4000; in = Wv; out = WvT; R = CENC; by = tt / 20; bx = tt % 20; }
  const int by64 = by * 64, bx64 = bx * 64;
  const int tx = t & 63;
  const int ty = t >> 6;            // 0..3
#pragma unroll
  for (int r = 0; r < 16; ++r) {
    const int row = ty + r * 4;     // 0..63
    tile[row][tx] = in[(size_t)(by64 + row) * CDIM + bx64 + tx];
  }
  __syncthreads();
  const int c4 = t & 15;            // 4-col group within 64
  const int j0 = t >> 4;            // 0..15
#pragma unroll
  for (int k = 0; k < 4; ++k) {
    const int j = j0 + k * 16;      // output row within tile (input col)
    ushort4 w;
    w.x = f2b(tile[c4 * 4 + 0][j]);
    w.y = f2b(tile[c4 * 4 + 1][j]);
    w.z = f2b(tile[c4 * 4 + 2][j]);
    w.w = f2b(tile[c4 * 4 + 3][j]);
    *(ushort4*)&out[(size_t)(bx64 + j) * R + by64 + c4 * 4] = w;
  }
}

// ---------------- fused Q-proj GEMM + attention ----------------
// A = Xb [8192][1280] bf16, BT = WqT [1280][1280]; per block: 128 q-rows x 2 heads.
// Epilogue: q stays in LDS, QK^T / max-free softmax / PV against kp/vtp.
__global__ __launch_bounds__(256, 3) void gemm_q_attn(
    const unsigned short* __restrict__ A, const unsigned short* __restrict__ BT,
    const unsigned short* __restrict__ kp, const unsigned short* __restrict__ vtp,
    unsigned short* __restrict__ ao) {
  __shared__ __align__(16) unsigned short ldsA[128 * 64];
  __shared__ __align__(16) unsigned short ldsB[128 * 64];
  __shared__ __align__(16) unsigned short ldsP[4][16 * 104];
  const int t = threadIdx.x;
  const int lane = t & 63;
  const int wave = t >> 6;
  const int lin = blockIdx.x;
  const int nwg = gridDim.x;                 // 640, %8==0
  const int q8 = nwg >> 3;
  const int xcd = lin & 7, sub = lin >> 3;
  const int wg = xcd * q8 + sub;             // bijective (nwg%8==0)
  const int ntile = CDIM >> 7;               // 10
  const int m0 = (wg / ntile) * 128;
  const int n0 = (wg % ntile) * 128;
  const int wr0 = (wave >> 1) * 64;
  const int wc0 = (wave & 1) * 64;
  const int lr = lane & 15;
  const int kg = lane >> 4;
  const int srow = t >> 3;
  const int sslot = t & 7;

  f32x4 acc[4][4] = {};

  for (int k0 = 0; k0 < CDIM; k0 += 64) {
#pragma unroll
    for (int c = 0; c < 4; ++c) {
      const int row = c * 32 + srow;
      const int slot = sslot ^ (row & 7);   // pre-swizzled global source
      const unsigned short* ga = A  + (size_t)(m0 + row) * CDIM + k0 + slot * 8;
      const unsigned short* gb = BT + (size_t)(n0 + row) * CDIM + k0 + slot * 8;
      __builtin_amdgcn_global_load_lds((gu32*)ga, (lu32*)&ldsA[c * 2048 + wave * 512], 16, 0, 0);
      __builtin_amdgcn_global_load_lds((gu32*)gb, (lu32*)&ldsB[c * 2048 + wave * 512], 16, 0, 0);
    }
    __syncthreads();
#pragma unroll
    for (int s = 0; s < 2; ++s) {
      const int slot = s * 4 + kg;
      bf16x8 af[4], bf[4];
#pragma unroll
      for (int i = 0; i < 4; ++i) {
        const int r = wr0 + i * 16 + lr;
        af[i] = *(const bf16x8*)&ldsA[r * 64 + (slot ^ (r & 7)) * 8];
        const int n = wc0 + i * 16 + lr;
        bf[i] = *(const bf16x8*)&ldsB[n * 64 + (slot ^ (n & 7)) * 8];
      }
#pragma unroll
      for (int i = 0; i < 4; ++i)
#pragma unroll
        for (int j = 0; j < 4; ++j)
          acc[i][j] = mfma16(af[i], bf[j], acc[i][j]);
    }
    __syncthreads();
  }
  // after this barrier all LDS reads are drained; quadrants become wave-private.

  // ---- q (bf16-rounded) -> per-wave LDS quadrant, same XOR-8 slot swizzle ----
  unsigned short* ldsQ = (wave < 2) ? (ldsA + wave * 4096) : (ldsB + (wave - 2) * 4096);
#pragma unroll
  for (int j = 0; j < 4; ++j)
#pragma unroll
    for (int i = 0; i < 4; ++i)
#pragma unroll
      for (int r = 0; r < 4; ++r) {
        const int row = i * 16 + kg * 4 + r;      // 0..63 within wave
        const int d = j * 16 + lr;                // 0..63
        const int slot = (d >> 3) ^ (row & 7);
        ldsQ[row * 64 + slot * 8 + (d & 7)] = f2b(acc[i][j][r]);
      }

  const int h = n0 / 64 + (wave & 1);             // global head 0..19
  const int b = m0 >> 12;                          // SQL = 4096
  const int bh = b * NH + h;
  unsigned short* Pw = ldsP[wave];

  // K and V fragments are rg-invariant: hoist
  bf16x8 kfr[5][2];
#pragma unroll
  for (int n = 0; n < 5; ++n)
#pragma unroll
    for (int s = 0; s < 2; ++s)
      kfr[n][s] = *(const bf16x8*)&kp[((size_t)bh * KVP + n * 16 + lr) * DHD + s * 32 + kg * 8];
  bf16x8 vfr[4][3];
#pragma unroll
  for (int dsub = 0; dsub < 4; ++dsub)
#pragma unroll
    for (int s = 0; s < 3; ++s)
      vfr[dsub][s] = *(const bf16x8*)&vtp[((size_t)bh * DHD + dsub * 16 + lr) * KVP + s * 32 + kg * 8];

#pragma unroll 1
  for (int rg = 0; rg < 4; ++rg) {
    // q fragments from LDS
    bf16x8 qa[2];
#pragma unroll
    for (int s = 0; s < 2; ++s) {
      const int row = rg * 16 + lr;
      const int slot = (s * 4 + kg) ^ (row & 7);
      qa[s] = *(const bf16x8*)&ldsQ[row * 64 + slot * 8];
    }
    // QK^T
    f32x4 sc[5];
    __builtin_amdgcn_s_setprio(1);
#pragma unroll
    for (int n = 0; n < 5; ++n) {
      f32x4 a = {};
#pragma unroll
      for (int s = 0; s < 2; ++s)
        a = mfma16(qa[s], kfr[n][s], a);
      sc[n] = a;
    }
    __builtin_amdgcn_s_setprio(0);

    // max-free softmax; 1/sum folded into PV output (same lane/row)
    float pv[5][4];
    float inv[4];
#pragma unroll
    for (int reg = 0; reg < 4; ++reg) {
      float sum = 0.f;
#pragma unroll
      for (int n = 0; n < 4; ++n) {        // kv = n*16+lr <= 63 < 77: no mask
        const float p = __expf(sc[n][reg] * SCALE);
        pv[n][reg] = p;
        sum += p;
      }
      {                                     // n=4: kv = 64+lr, valid iff lr<13
        const float p = (lr < 13) ? __expf(sc[4][reg] * SCALE) : 0.f;
        pv[4][reg] = p;
        sum += p;
      }
      sum += __shfl_xor(sum, 1);
      sum += __shfl_xor(sum, 2);
      sum += __shfl_xor(sum, 4);
      sum += __shfl_xor(sum, 8);
      inv[reg] = 1.f / sum;
    }

    // P -> LDS bf16 (unnormalized), zero pad cols 80..95
#pragma unroll
    for (int reg = 0; reg < 4; ++reg) {
      const int row = kg * 4 + reg;
#pragma unroll
      for (int n = 0; n < 5; ++n)
        Pw[row * 104 + n * 16 + lr] = f2b(pv[n][reg]);
      Pw[row * 104 + 80 + lr] = 0;
    }

    // PV
    bf16x8 pa[3];
#pragma unroll
    for (int s = 0; s < 3; ++s)
      pa[s] = *(const bf16x8*)&Pw[lr * 104 + s * 32 + kg * 8];
    __builtin_amdgcn_s_setprio(1);
#pragma unroll
    for (int dsub = 0; dsub < 4; ++dsub) {
      f32x4 o = {};
#pragma unroll
      for (int s = 0; s < 3; ++s)
        o = mfma16(pa[s], vfr[dsub][s], o);
#pragma unroll
      for (int reg = 0; reg < 4; ++reg)
        ao[(size_t)(m0 + wr0 + rg * 16 + kg * 4 + reg) * CDIM + h * DHD + dsub * 16 + lr] =
            f2b(o[reg] * inv[reg]);
    }
    __builtin_amdgcn_s_setprio(0);
  }
}

// ---------------- O-proj GEMM: C[M][N] = A[M][K] * BT[N][K]^T, f32 out + bias
__global__ __launch_bounds__(256, 4) void gemm_bt(
    const unsigned short* __restrict__ A, const unsigned short* __restrict__ BT,
    float* __restrict__ Cf, const float* __restrict__ bias, int M, int N, int K) {
  __shared__ __align__(16) unsigned short ldsA[128 * 64];
  __shared__ __align__(16) unsigned short ldsB[128 * 64];
  const int t = threadIdx.x;
  const int lane = t & 63;
  const int wave = t >> 6;
  const int lin = blockIdx.x;
  const int nwg = gridDim.x;
  const int q8 = nwg >> 3, r8 = nwg & 7;
  const int xcd = lin & 7, sub = lin >> 3;
  const int wg = (xcd < r8 ? xcd * (q8 + 1) : r8 * (q8 + 1) + (xcd - r8) * q8) + sub;
  const int ntile = N >> 7;
  const int m0 = (wg / ntile) * 128;
  const int n0 = (wg % ntile) * 128;
  const int wr0 = (wave >> 1) * 64;
  const int wc0 = (wave & 1) * 64;
  const int lr = lane & 15;
  const int kg = lane >> 4;
  const int srow = t >> 3;
  const int sslot = t & 7;

  f32x4 acc[4][4] = {};

  for (int k0 = 0; k0 < K; k0 += 64) {
#pragma unroll
    for (int c = 0; c < 4; ++c) {
      const int row = c * 32 + srow;
      const int slot = sslot ^ (row & 7);
      const unsigned short* ga = A  + (size_t)(m0 + row) * K + k0 + slot * 8;
      const unsigned short* gb = BT + (size_t)(n0 + row) * K + k0 + slot * 8;
      __builtin_amdgcn_global_load_lds((gu32*)ga, (lu32*)&ldsA[c * 2048 + wave * 512], 16, 0, 0);
      __builtin_amdgcn_global_load_lds((gu32*)gb, (lu32*)&ldsB[c * 2048 + wave * 512], 16, 0, 0);
    }
    __syncthreads();
#pragma unroll
    for (int s = 0; s < 2; ++s) {
      const int slot = s * 4 + kg;
      bf16x8 af[4], bf[4];
#pragma unroll
      for (int i = 0; i < 4; ++i) {
        const int r = wr0 + i * 16 + lr;
        af[i] = *(const bf16x8*)&ldsA[r * 64 + (slot ^ (r & 7)) * 8];
        const int n = wc0 + i * 16 + lr;
        bf[i] = *(const bf16x8*)&ldsB[n * 64 + (slot ^ (n & 7)) * 8];
      }
#pragma unroll
      for (int i = 0; i < 4; ++i)
#pragma unroll
        for (int j = 0; j < 4; ++j)
          acc[i][j] = mfma16(af[i], bf[j], acc[i][j]);
    }
    __syncthreads();
  }

#pragma unroll
  for (int j = 0; j < 4; ++j) {
    const int col = n0 + wc0 + j * 16 + lr;
    const float bj = bias[col];
#pragma unroll
    for (int i = 0; i < 4; ++i)
#pragma unroll
      for (int r = 0; r < 4; ++r) {
        const int row = m0 + wr0 + i * 16 + kg * 4 + r;
        Cf[(size_t)row * N + col] = acc[i][j][r] + bj;
      }
  }
}

// ---------------- fused K/V projection, split-K x4 -> f32 partials pk[z][256][1280]
__global__ __launch_bounds__(256) void gemm_kv(
    const unsigned short* __restrict__ A, const unsigned short* __restrict__ BTk,
    const unsigned short* __restrict__ BTv, float* __restrict__ pk) {
  __shared__ __align__(16) unsigned short ldsA[128 * 64];
  __shared__ __align__(16) unsigned short ldsB[128 * 64];
  const int t = threadIdx.x;
  const int lane = t & 63;
  const int wave = t >> 6;
  const int z = blockIdx.z;            // out*4 + ks
  const unsigned short* BT = (z >> 2) ? BTv : BTk;
  const int ks = z & 3;
  const int m0 = blockIdx.x * 128;
  const int n0 = blockIdx.y * 128;
  float* C = pk + (size_t)z * 256 * CDIM;
  const int wr0 = (wave >> 1) * 64;
  const int wc0 = (wave & 1) * 64;
  const int lr = lane & 15;
  const int kg = lane >> 4;
  const int srow = t >> 3;
  const int sslot = t & 7;

  f32x4 acc[4][4] = {};

  for (int k0 = ks * 512; k0 < (ks + 1) * 512; k0 += 64) {
#pragma unroll
    for (int c = 0; c < 4; ++c) {
      const int row = c * 32 + srow;
      const int slot = sslot ^ (row & 7);
      const unsigned short* ga = A  + (size_t)(m0 + row) * CENC + k0 + slot * 8;
      const unsigned short* gb = BT + (size_t)(n0 + row) * CENC + k0 + slot * 8;
      __builtin_amdgcn_global_load_lds((gu32*)ga, (lu32*)&ldsA[c * 2048 + wave * 512], 16, 0, 0);
      __builtin_amdgcn_global_load_lds((gu32*)gb, (lu32*)&ldsB[c * 2048 + wave * 512], 16, 0, 0);
    }
    __syncthreads();
#pragma unroll
    for (int s = 0; s < 2; ++s) {
      const int slot = s * 4 + kg;
      bf16x8 af[4], bf[4];
#pragma unroll
      for (int i = 0; i < 4; ++i) {
        const int r = wr0 + i * 16 + lr;
        af[i] = *(const bf16x8*)&ldsA[r * 64 + (slot ^ (r & 7)) * 8];
        const int n = wc0 + i * 16 + lr;
        bf[i] = *(const bf16x8*)&ldsB[n * 64 + (slot ^ (n & 7)) * 8];
      }
#pragma unroll
      for (int i = 0; i < 4; ++i)
#pragma unroll
        for (int j = 0; j < 4; ++j)
          acc[i][j] = mfma16(af[i], bf[j], acc[i][j]);
    }
    __syncthreads();
  }

#pragma unroll
  for (int j = 0; j < 4; ++j) {
    const int col = n0 + wc0 + j * 16 + lr;
#pragma unroll
    for (int i = 0; i < 4; ++i)
#pragma unroll
      for (int r = 0; r < 4; ++r) {
        const int row = m0 + wr0 + i * 16 + kg * 4 + r;
        C[(size_t)row * CDIM + col] = acc[i][j][r];
      }
  }
}

// ---------------- CORA erase + split-K reduce + K pack + zero-padding (grid BATCH*96)
__global__ __launch_bounds__(256) void cora_kernel(
    const float* __restrict__ pk, const float* __restrict__ Bp,
    const float* __restrict__ uh, const float* __restrict__ ah,
    unsigned short* __restrict__ vtp, unsigned short* __restrict__ kp) {
  const int bs = blockIdx.x;
  const int b = bs / KVP;
  const int s = bs % KVP;
  const int t = threadIdx.x;
  if (s >= SKV) {   // pad rows: zero vtp and kp
#pragma unroll
    for (int e = 0; e < 5; ++e) {
      const int hh = t + e * 256;
      const int head = hh >> 6, d = hh & 63;
      vtp[(((size_t)b * NH + head) * DHD + d) * KVP + s] = 0;
      kp[(((size_t)b * NH + head) * KVP + s) * DHD + d] = 0;
    }
    return;
  }
  const int rbs = b * SKV + s;
  const int lane = t & 63;
  const int wave = t >> 6;
  const int STR = 256 * CDIM;
  __shared__ float red1[4][4];
  __shared__ float red2[4][2];
  float vv[5], vfr[5], vpr[5];
  float c0 = 0.f, c1 = 0.f, c2 = 0.f, c3 = 0.f;
#pragma unroll
  for (int e = 0; e < 5; ++e) {
    const int hh = t + e * 256;
    const float* base = pk + (size_t)rbs * CDIM + hh;
    const float kv_ = base[0] + base[STR] + base[2 * STR] + base[3 * STR];
    const int head = hh >> 6, d = hh & 63;
    kp[(((size_t)b * NH + head) * KVP + s) * DHD + d] = f2b(kv_);
    const float x = base[4 * STR] + base[5 * STR] + base[6 * STR] + base[7 * STR];
    vv[e] = x;
    const float* bp = Bp + ((size_t)s * CDIM + hh) * 4;
    c0 += x * bp[0]; c1 += x * bp[1]; c2 += x * bp[2]; c3 += x * bp[3];
  }
#pragma unroll
  for (int d = 32; d >= 1; d >>= 1) {
    c0 += __shfl_xor(c0, d); c1 += __shfl_xor(c1, d);
    c2 += __shfl_xor(c2, d); c3 += __shfl_xor(c3, d);
  }
  if (lane == 0) { red1[wave][0] = c0; red1[wave][1] = c1; red1[wave][2] = c2; red1[wave][3] = c3; }
  __syncthreads();
  c0 = red1[0][0] + red1[1][0] + red1[2][0] + red1[3][0];
  c1 = red1[0][1] + red1[1][1] + red1[2][1] + red1[3][1];
  c2 = red1[0][2] + red1[1][2] + red1[2][2] + red1[3][2];
  c3 = red1[0][3] + red1[1][3] + red1[2][3] + red1[3][3];
  float tp = 0.f, np = 0.f;
#pragma unroll
  for (int e = 0; e < 5; ++e) {
    const int hh = t + e * 256;
    const float* bp = Bp + ((size_t)s * CDIM + hh) * 4;
    const float vp = c0 * bp[0] + c1 * bp[1] + c2 * bp[2] + c3 * bp[3];
    const float fr = vv[e] - vp;
    vpr[e] = vp; vfr[e] = fr;
    tp += fr * uh[(size_t)s * CDIM + hh];
    np += fr * fr;
  }
#pragma unroll
  for (int d = 32; d >= 1; d >>= 1) { tp += __shfl_xor(tp, d); np += __shfl_xor(np, d); }
  if (lane == 0) { red2[wave][0] = tp; red2[wave][1] = np; }
  __syncthreads();
  const float tt = red2[0][0] + red2[1][0] + red2[2][0] + red2[3][0];
  const float nn = red2[0][1] + red2[1][1] + red2[2][1] + red2[3][1];
  const float denom = sqrtf(nn) + 1e-8f;
  const bool gate = fabsf(tt) >= TAUC * denom;   // frac >= TAU
#pragma unroll
  for (int e = 0; e < 5; ++e) {
    const int hh = t + e * 256;
    float o = vfr[e];
    if (gate) o = o - tt * uh[(size_t)s * CDIM + hh] + BETAC * tt * ah[(size_t)s * CDIM + hh];
    o += vpr[e];
    const int head = hh >> 6, d = hh & 63;
    vtp[(((size_t)b * NH + head) * DHD + d) * KVP + s] = f2b(o);
  }
}

// ---------------- launch ----------------

extern "C" void kernel_launch(void* const* d_in, const int* in_sizes, int n_in,
                              void* d_out, int out_size, void* d_ws, size_t ws_size,
                              hipStream_t stream) {
  const float* X   = (const float*)d_in[0];
  const float* enc = (const float*)d_in[1];
  const float* Wq  = (const float*)d_in[2];
  const float* Wk  = (const float*)d_in[3];
  const float* Wv  = (const float*)d_in[4];
  const float* Wo  = (const float*)d_in[5];
  const float* bo  = (const float*)d_in[6];
  const float* Bp  = (const float*)d_in[7];
  const float* uh  = (const float*)d_in[8];
  const float* ah  = (const float*)d_in[9];
  float* out = (float*)d_out;

  char* w = (char*)d_ws;
  unsigned short* Xb   = (unsigned short*)(w);                // 8192*1280 bf16
  unsigned short* attn = (unsigned short*)(w + 20971520);     // 8192*1280 bf16 (attn out)
  float*          pk   = (float*)         (w + 20971520);     // alias: 8*256*1280 f32, dead before attn written
  unsigned short* WqT  = (unsigned short*)(w + 41943040);     // 1280*1280 bf16
  unsigned short* WoT  = (unsigned short*)(w + 45219840);     // 1280*1280 bf16
  unsigned short* WkT  = (unsigned short*)(w + 48496640);     // 1280*2048 bf16
  unsigned short* WvT  = (unsigned short*)(w + 53739520);     // 1280*2048 bf16
  unsigned short* encb = (unsigned short*)(w + 58982400);     // 256*2048 bf16
  unsigned short* kp   = (unsigned short*)(w + 61997056);     // 2*20*96*64 bf16
  unsigned short* vtp  = (unsigned short*)(w + 62488576);     // 2*20*64*96 bf16
  // total 62,980,096 B

  prep_trans_kernel<<<4640, 256, 0, stream>>>(X, Xb, enc, encb,
      Wq, WqT, Wo, WoT, Wk, WkT, Wv, WvT);

  gemm_kv<<<dim3(2, 10, 8), 256, 0, stream>>>(encb, WkT, WvT, pk);
  cora_kernel<<<BATCH * KVP, 256, 0, stream>>>(pk, Bp, uh, ah, vtp, kp);

  gemm_q_attn<<<640, 256, 0, stream>>>(Xb, WqT, kp, vtp, attn);
  gemm_bt<<<640, 256, 0, stream>>>(attn, WoT, out, bo, BATCH * SQL, CDIM, CDIM);
}

// Round 12
// 114.712 us; speedup vs baseline: 3.1321x; 1.0244x over previous
//
#include <hip/hip_runtime.h>

#define BATCH 2
#define SQL   4096
#define CDIM  1280
#define SKV   77
#define CENC  2048
#define NH    20
#define DHD   64
#define KVP   96        // kv padded to 3*32 for MFMA K
#define SCALE 0.125f
#define TAUC  0.1f
#define BETAC 0.5f

typedef __attribute__((ext_vector_type(4))) float  f32x4;
typedef __attribute__((ext_vector_type(8))) __bf16 bf16x8;

typedef __attribute__((address_space(1))) unsigned int gu32;
typedef __attribute__((address_space(3))) unsigned int lu32;

__device__ __forceinline__ unsigned short f2b(float x) {
  union { float f; unsigned u; } a; a.f = x;
  unsigned r = a.u + 0x7FFFu + ((a.u >> 16) & 1u);
  return (unsigned short)(r >> 16);
}

__device__ __forceinline__ f32x4 mfma16(bf16x8 a, bf16x8 b, f32x4 c) {
  return __builtin_amdgcn_mfma_f32_16x16x32_bf16(a, b, c, 0, 0, 0);
}

// ---------------- prep: enc pad->bf16 + 4 weight transposes (64x64 tiles) ----------------
// grid: [0,512) enc pad; [512,912) Wq; [912,1312) Wo; [1312,1952) Wk; [1952,2592) Wv.
__global__ __launch_bounds__(256) void prep_trans_kernel(
    const float* __restrict__ enc, unsigned short* __restrict__ encb,
    const float* __restrict__ Wq, unsigned short* __restrict__ WqT,
    const float* __restrict__ Wo, unsigned short* __restrict__ WoT,
    const float* __restrict__ Wk, unsigned short* __restrict__ WkT,
    const float* __restrict__ Wv, unsigned short* __restrict__ WvT) {
  __shared__ float tile[64][65];
  const int bid = blockIdx.x;
  const int t = threadIdx.x;
  if (bid < 512) {
    const int i = bid * 256 + t;  // 131072 f4 groups
    float4 v; v.x = 0.f; v.y = 0.f; v.z = 0.f; v.w = 0.f;
    if (i < (BATCH * SKV) * (CENC / 4)) v = ((const float4*)enc)[i];
    ushort4 o;
    o.x = f2b(v.x); o.y = f2b(v.y); o.z = f2b(v.z); o.w = f2b(v.w);
    ((ushort4*)encb)[i] = o;
    return;
  }
  const float* in;
  unsigned short* out;
  int R, by, bx;
  if (bid < 912)       { const int tt = bid - 512;  in = Wq; out = WqT; R = CDIM; by = tt / 20; bx = tt % 20; }
  else if (bid < 1312) { const int tt = bid - 912;  in = Wo; out = WoT; R = CDIM; by = tt / 20; bx = tt % 20; }
  else if (bid < 1952) { const int tt = bid - 1312; in = Wk; out = WkT; R = CENC; by = tt / 20; bx = tt % 20; }
  else                 { const int tt = bid - 1952; in = Wv; out = WvT; R = CENC; by = tt / 20; bx = tt % 20; }
  const int by64 = by * 64, bx64 = bx * 64;
  const int tx = t & 63;
  const int ty = t >> 6;            // 0..3
#pragma unroll
  for (int r = 0; r < 16; ++r) {
    const int row = ty + r * 4;     // 0..63
    tile[row][tx] = in[(size_t)(by64 + row) * CDIM + bx64 + tx];
  }
  __syncthreads();
  const int c4 = t & 15;            // 4-col group within 64
  const int j0 = t >> 4;            // 0..15
#pragma unroll
  for (int k = 0; k < 4; ++k) {
    const int j = j0 + k * 16;      // output row within tile (input col)
    ushort4 w;
    w.x = f2b(tile[c4 * 4 + 0][j]);
    w.y = f2b(tile[c4 * 4 + 1][j]);
    w.z = f2b(tile[c4 * 4 + 2][j]);
    w.w = f2b(tile[c4 * 4 + 3][j]);
    *(ushort4*)&out[(size_t)(bx64 + j) * R + by64 + c4 * 4] = w;
  }
}

// ---------------- fused: K/V projection (split-K x4, blocks 0..159) + X->bf16 conv
// (blocks 160..2207, grid-stride). Independent work co-dispatched to fill idle CUs.
__global__ __launch_bounds__(256) void gemm_kv_xconv(
    const unsigned short* __restrict__ A, const unsigned short* __restrict__ BTk,
    const unsigned short* __restrict__ BTv, float* __restrict__ pk,
    const float* __restrict__ X, unsigned short* __restrict__ Xb) {
  const int bid = blockIdx.x;
  const int t = threadIdx.x;
  if (bid >= 160) {
    const int vb = bid - 160;                 // 2048 conv blocks
    const int n4 = (BATCH * SQL * CDIM) / 4;
    for (int i = vb * 256 + t; i < n4; i += 2048 * 256) {
      const float4 v = ((const float4*)X)[i];
      ushort4 o;
      o.x = f2b(v.x); o.y = f2b(v.y); o.z = f2b(v.z); o.w = f2b(v.w);
      ((ushort4*)Xb)[i] = o;
    }
    return;
  }
  __shared__ __align__(16) unsigned short ldsA[128 * 64];
  __shared__ __align__(16) unsigned short ldsB[128 * 64];
  const int lane = t & 63;
  const int wave = t >> 6;
  const int z = bid / 20;              // out*4 + ks
  const int y = (bid % 20) >> 1;       // n-tile 0..9
  const int xm = bid & 1;              // m-tile 0..1
  const unsigned short* BT = (z >> 2) ? BTv : BTk;
  const int ks = z & 3;
  const int m0 = xm * 128;
  const int n0 = y * 128;
  float* C = pk + (size_t)z * 256 * CDIM;
  const int wr0 = (wave >> 1) * 64;
  const int wc0 = (wave & 1) * 64;
  const int lr = lane & 15;
  const int kg = lane >> 4;
  const int srow = t >> 3;
  const int sslot = t & 7;

  f32x4 acc[4][4] = {};

  for (int k0 = ks * 512; k0 < (ks + 1) * 512; k0 += 64) {
#pragma unroll
    for (int c = 0; c < 4; ++c) {
      const int row = c * 32 + srow;
      const int slot = sslot ^ (row & 7);
      const unsigned short* ga = A  + (size_t)(m0 + row) * CENC + k0 + slot * 8;
      const unsigned short* gb = BT + (size_t)(n0 + row) * CENC + k0 + slot * 8;
      __builtin_amdgcn_global_load_lds((gu32*)ga, (lu32*)&ldsA[c * 2048 + wave * 512], 16, 0, 0);
      __builtin_amdgcn_global_load_lds((gu32*)gb, (lu32*)&ldsB[c * 2048 + wave * 512], 16, 0, 0);
    }
    __syncthreads();
#pragma unroll
    for (int s = 0; s < 2; ++s) {
      const int slot = s * 4 + kg;
      bf16x8 af[4], bf[4];
#pragma unroll
      for (int i = 0; i < 4; ++i) {
        const int r = wr0 + i * 16 + lr;
        af[i] = *(const bf16x8*)&ldsA[r * 64 + (slot ^ (r & 7)) * 8];
        const int n = wc0 + i * 16 + lr;
        bf[i] = *(const bf16x8*)&ldsB[n * 64 + (slot ^ (n & 7)) * 8];
      }
#pragma unroll
      for (int i = 0; i < 4; ++i)
#pragma unroll
        for (int j = 0; j < 4; ++j)
          acc[i][j] = mfma16(af[i], bf[j], acc[i][j]);
    }
    __syncthreads();
  }

#pragma unroll
  for (int j = 0; j < 4; ++j) {
    const int col = n0 + wc0 + j * 16 + lr;
#pragma unroll
    for (int i = 0; i < 4; ++i)
#pragma unroll
      for (int r = 0; r < 4; ++r) {
        const int row = m0 + wr0 + i * 16 + kg * 4 + r;
        C[(size_t)row * CDIM + col] = acc[i][j][r];
      }
  }
}

// ---------------- fused Q-proj GEMM + attention ----------------
// A = Xb [8192][1280] bf16, BT = WqT [1280][1280]; per block: 128 q-rows x 2 heads.
// Epilogue: q stays in LDS, QK^T / max-free softmax / PV against kp/vtp.
__global__ __launch_bounds__(256, 3) void gemm_q_attn(
    const unsigned short* __restrict__ A, const unsigned short* __restrict__ BT,
    const unsigned short* __restrict__ kp, const unsigned short* __restrict__ vtp,
    unsigned short* __restrict__ ao) {
  __shared__ __align__(16) unsigned short ldsA[128 * 64];
  __shared__ __align__(16) unsigned short ldsB[128 * 64];
  __shared__ __align__(16) unsigned short ldsP[4][16 * 104];
  const int t = threadIdx.x;
  const int lane = t & 63;
  const int wave = t >> 6;
  const int lin = blockIdx.x;
  const int nwg = gridDim.x;                 // 640, %8==0
  const int q8 = nwg >> 3;
  const int xcd = lin & 7, sub = lin >> 3;
  const int wg = xcd * q8 + sub;             // bijective (nwg%8==0)
  const int ntile = CDIM >> 7;               // 10
  const int m0 = (wg / ntile) * 128;
  const int n0 = (wg % ntile) * 128;
  const int wr0 = (wave >> 1) * 64;
  const int wc0 = (wave & 1) * 64;
  const int lr = lane & 15;
  const int kg = lane >> 4;
  const int srow = t >> 3;
  const int sslot = t & 7;

  f32x4 acc[4][4] = {};

  for (int k0 = 0; k0 < CDIM; k0 += 64) {
#pragma unroll
    for (int c = 0; c < 4; ++c) {
      const int row = c * 32 + srow;
      const int slot = sslot ^ (row & 7);   // pre-swizzled global source
      const unsigned short* ga = A  + (size_t)(m0 + row) * CDIM + k0 + slot * 8;
      const unsigned short* gb = BT + (size_t)(n0 + row) * CDIM + k0 + slot * 8;
      __builtin_amdgcn_global_load_lds((gu32*)ga, (lu32*)&ldsA[c * 2048 + wave * 512], 16, 0, 0);
      __builtin_amdgcn_global_load_lds((gu32*)gb, (lu32*)&ldsB[c * 2048 + wave * 512], 16, 0, 0);
    }
    __syncthreads();
#pragma unroll
    for (int s = 0; s < 2; ++s) {
      const int slot = s * 4 + kg;
      bf16x8 af[4], bf[4];
#pragma unroll
      for (int i = 0; i < 4; ++i) {
        const int r = wr0 + i * 16 + lr;
        af[i] = *(const bf16x8*)&ldsA[r * 64 + (slot ^ (r & 7)) * 8];
        const int n = wc0 + i * 16 + lr;
        bf[i] = *(const bf16x8*)&ldsB[n * 64 + (slot ^ (n & 7)) * 8];
      }
#pragma unroll
      for (int i = 0; i < 4; ++i)
#pragma unroll
        for (int j = 0; j < 4; ++j)
          acc[i][j] = mfma16(af[i], bf[j], acc[i][j]);
    }
    __syncthreads();
  }
  // after this barrier all LDS reads are drained; quadrants become wave-private.

  // ---- q (bf16-rounded) -> per-wave LDS quadrant, same XOR-8 slot swizzle ----
  unsigned short* ldsQ = (wave < 2) ? (ldsA + wave * 4096) : (ldsB + (wave - 2) * 4096);
#pragma unroll
  for (int j = 0; j < 4; ++j)
#pragma unroll
    for (int i = 0; i < 4; ++i)
#pragma unroll
      for (int r = 0; r < 4; ++r) {
        const int row = i * 16 + kg * 4 + r;      // 0..63 within wave
        const int d = j * 16 + lr;                // 0..63
        const int slot = (d >> 3) ^ (row & 7);
        ldsQ[row * 64 + slot * 8 + (d & 7)] = f2b(acc[i][j][r]);
      }

  const int h = n0 / 64 + (wave & 1);             // global head 0..19
  const int b = m0 >> 12;                          // SQL = 4096
  const int bh = b * NH + h;
  unsigned short* Pw = ldsP[wave];

  // K and V fragments are rg-invariant: hoist
  bf16x8 kfr[5][2];
#pragma unroll
  for (int n = 0; n < 5; ++n)
#pragma unroll
    for (int s = 0; s < 2; ++s)
      kfr[n][s] = *(const bf16x8*)&kp[((size_t)bh * KVP + n * 16 + lr) * DHD + s * 32 + kg * 8];
  bf16x8 vfr[4][3];
#pragma unroll
  for (int dsub = 0; dsub < 4; ++dsub)
#pragma unroll
    for (int s = 0; s < 3; ++s)
      vfr[dsub][s] = *(const bf16x8*)&vtp[((size_t)bh * DHD + dsub * 16 + lr) * KVP + s * 32 + kg * 8];

#pragma unroll 1
  for (int rg = 0; rg < 4; ++rg) {
    // q fragments from LDS
    bf16x8 qa[2];
#pragma unroll
    for (int s = 0; s < 2; ++s) {
      const int row = rg * 16 + lr;
      const int slot = (s * 4 + kg) ^ (row & 7);
      qa[s] = *(const bf16x8*)&ldsQ[row * 64 + slot * 8];
    }
    // QK^T
    f32x4 sc[5];
    __builtin_amdgcn_s_setprio(1);
#pragma unroll
    for (int n = 0; n < 5; ++n) {
      f32x4 a = {};
#pragma unroll
      for (int s = 0; s < 2; ++s)
        a = mfma16(qa[s], kfr[n][s], a);
      sc[n] = a;
    }
    __builtin_amdgcn_s_setprio(0);

    // max-free softmax; 1/sum folded into PV output (same lane/row)
    float pv[5][4];
    float inv[4];
#pragma unroll
    for (int reg = 0; reg < 4; ++reg) {
      float sum = 0.f;
#pragma unroll
      for (int n = 0; n < 4; ++n) {        // kv = n*16+lr <= 63 < 77: no mask
        const float p = __expf(sc[n][reg] * SCALE);
        pv[n][reg] = p;
        sum += p;
      }
      {                                     // n=4: kv = 64+lr, valid iff lr<13
        const float p = (lr < 13) ? __expf(sc[4][reg] * SCALE) : 0.f;
        pv[4][reg] = p;
        sum += p;
      }
      sum += __shfl_xor(sum, 1);
      sum += __shfl_xor(sum, 2);
      sum += __shfl_xor(sum, 4);
      sum += __shfl_xor(sum, 8);
      inv[reg] = 1.f / sum;
    }

    // P -> LDS bf16 (unnormalized), zero pad cols 80..95
#pragma unroll
    for (int reg = 0; reg < 4; ++reg) {
      const int row = kg * 4 + reg;
#pragma unroll
      for (int n = 0; n < 5; ++n)
        Pw[row * 104 + n * 16 + lr] = f2b(pv[n][reg]);
      Pw[row * 104 + 80 + lr] = 0;
    }

    // PV
    bf16x8 pa[3];
#pragma unroll
    for (int s = 0; s < 3; ++s)
      pa[s] = *(const bf16x8*)&Pw[lr * 104 + s * 32 + kg * 8];
    __builtin_amdgcn_s_setprio(1);
#pragma unroll
    for (int dsub = 0; dsub < 4; ++dsub) {
      f32x4 o = {};
#pragma unroll
      for (int s = 0; s < 3; ++s)
        o = mfma16(pa[s], vfr[dsub][s], o);
#pragma unroll
      for (int reg = 0; reg < 4; ++reg)
        ao[(size_t)(m0 + wr0 + rg * 16 + kg * 4 + reg) * CDIM + h * DHD + dsub * 16 + lr] =
            f2b(o[reg] * inv[reg]);
    }
    __builtin_amdgcn_s_setprio(0);
  }
}

// ---------------- O-proj GEMM: C[M][N] = A[M][K] * BT[N][K]^T, f32 out + bias
__global__ __launch_bounds__(256, 4) void gemm_bt(
    const unsigned short* __restrict__ A, const unsigned short* __restrict__ BT,
    float* __restrict__ Cf, const float* __restrict__ bias, int M, int N, int K) {
  __shared__ __align__(16) unsigned short ldsA[128 * 64];
  __shared__ __align__(16) unsigned short ldsB[128 * 64];
  const int t = threadIdx.x;
  const int lane = t & 63;
  const int wave = t >> 6;
  const int lin = blockIdx.x;
  const int nwg = gridDim.x;
  const int q8 = nwg >> 3, r8 = nwg & 7;
  const int xcd = lin & 7, sub = lin >> 3;
  const int wg = (xcd < r8 ? xcd * (q8 + 1) : r8 * (q8 + 1) + (xcd - r8) * q8) + sub;
  const int ntile = N >> 7;
  const int m0 = (wg / ntile) * 128;
  const int n0 = (wg % ntile) * 128;
  const int wr0 = (wave >> 1) * 64;
  const int wc0 = (wave & 1) * 64;
  const int lr = lane & 15;
  const int kg = lane >> 4;
  const int srow = t >> 3;
  const int sslot = t & 7;

  f32x4 acc[4][4] = {};

  for (int k0 = 0; k0 < K; k0 += 64) {
#pragma unroll
    for (int c = 0; c < 4; ++c) {
      const int row = c * 32 + srow;
      const int slot = sslot ^ (row & 7);
      const unsigned short* ga = A  + (size_t)(m0 + row) * K + k0 + slot * 8;
      const unsigned short* gb = BT + (size_t)(n0 + row) * K + k0 + slot * 8;
      __builtin_amdgcn_global_load_lds((gu32*)ga, (lu32*)&ldsA[c * 2048 + wave * 512], 16, 0, 0);
      __builtin_amdgcn_global_load_lds((gu32*)gb, (lu32*)&ldsB[c * 2048 + wave * 512], 16, 0, 0);
    }
    __syncthreads();
#pragma unroll
    for (int s = 0; s < 2; ++s) {
      const int slot = s * 4 + kg;
      bf16x8 af[4], bf[4];
#pragma unroll
      for (int i = 0; i < 4; ++i) {
        const int r = wr0 + i * 16 + lr;
        af[i] = *(const bf16x8*)&ldsA[r * 64 + (slot ^ (r & 7)) * 8];
        const int n = wc0 + i * 16 + lr;
        bf[i] = *(const bf16x8*)&ldsB[n * 64 + (slot ^ (n & 7)) * 8];
      }
#pragma unroll
      for (int i = 0; i < 4; ++i)
#pragma unroll
        for (int j = 0; j < 4; ++j)
          acc[i][j] = mfma16(af[i], bf[j], acc[i][j]);
    }
    __syncthreads();
  }

#pragma unroll
  for (int j = 0; j < 4; ++j) {
    const int col = n0 + wc0 + j * 16 + lr;
    const float bj = bias[col];
#pragma unroll
    for (int i = 0; i < 4; ++i)
#pragma unroll
      for (int r = 0; r < 4; ++r) {
        const int row = m0 + wr0 + i * 16 + kg * 4 + r;
        Cf[(size_t)row * N + col] = acc[i][j][r] + bj;
      }
  }
}

// ---------------- CORA erase + split-K reduce + K pack + zero-padding (grid BATCH*96)
__global__ __launch_bounds__(256) void cora_kernel(
    const float* __restrict__ pk, const float* __restrict__ Bp,
    const float* __restrict__ uh, const float* __restrict__ ah,
    unsigned short* __restrict__ vtp, unsigned short* __restrict__ kp) {
  const int bs = blockIdx.x;
  const int b = bs / KVP;
  const int s = bs % KVP;
  const int t = threadIdx.x;
  if (s >= SKV) {   // pad rows: zero vtp and kp
#pragma unroll
    for (int e = 0; e < 5; ++e) {
      const int hh = t + e * 256;
      const int head = hh >> 6, d = hh & 63;
      vtp[(((size_t)b * NH + head) * DHD + d) * KVP + s] = 0;
      kp[(((size_t)b * NH + head) * KVP + s) * DHD + d] = 0;
    }
    return;
  }
  const int rbs = b * SKV + s;
  const int lane = t & 63;
  const int wave = t >> 6;
  const int STR = 256 * CDIM;
  __shared__ float red1[4][4];
  __shared__ float red2[4][2];
  float vv[5], vfr[5], vpr[5];
  float c0 = 0.f, c1 = 0.f, c2 = 0.f, c3 = 0.f;
#pragma unroll
  for (int e = 0; e < 5; ++e) {
    const int hh = t + e * 256;
    const float* base = pk + (size_t)rbs * CDIM + hh;
    const float kv_ = base[0] + base[STR] + base[2 * STR] + base[3 * STR];
    const int head = hh >> 6, d = hh & 63;
    kp[(((size_t)b * NH + head) * KVP + s) * DHD + d] = f2b(kv_);
    const float x = base[4 * STR] + base[5 * STR] + base[6 * STR] + base[7 * STR];
    vv[e] = x;
    const float* bp = Bp + ((size_t)s * CDIM + hh) * 4;
    c0 += x * bp[0]; c1 += x * bp[1]; c2 += x * bp[2]; c3 += x * bp[3];
  }
#pragma unroll
  for (int d = 32; d >= 1; d >>= 1) {
    c0 += __shfl_xor(c0, d); c1 += __shfl_xor(c1, d);
    c2 += __shfl_xor(c2, d); c3 += __shfl_xor(c3, d);
  }
  if (lane == 0) { red1[wave][0] = c0; red1[wave][1] = c1; red1[wave][2] = c2; red1[wave][3] = c3; }
  __syncthreads();
  c0 = red1[0][0] + red1[1][0] + red1[2][0] + red1[3][0];
  c1 = red1[0][1] + red1[1][1] + red1[2][1] + red1[3][1];
  c2 = red1[0][2] + red1[1][2] + red1[2][2] + red1[3][2];
  c3 = red1[0][3] + red1[1][3] + red1[2][3] + red1[3][3];
  float tp = 0.f, np = 0.f;
#pragma unroll
  for (int e = 0; e < 5; ++e) {
    const int hh = t + e * 256;
    const float* bp = Bp + ((size_t)s * CDIM + hh) * 4;
    const float vp = c0 * bp[0] + c1 * bp[1] + c2 * bp[2] + c3 * bp[3];
    const float fr = vv[e] - vp;
    vpr[e] = vp; vfr[e] = fr;
    tp += fr * uh[(size_t)s * CDIM + hh];
    np += fr * fr;
  }
#pragma unroll
  for (int d = 32; d >= 1; d >>= 1) { tp += __shfl_xor(tp, d); np += __shfl_xor(np, d); }
  if (lane == 0) { red2[wave][0] = tp; red2[wave][1] = np; }
  __syncthreads();
  const float tt = red2[0][0] + red2[1][0] + red2[2][0] + red2[3][0];
  const float nn = red2[0][1] + red2[1][1] + red2[2][1] + red2[3][1];
  const float denom = sqrtf(nn) + 1e-8f;
  const bool gate = fabsf(tt) >= TAUC * denom;   // frac >= TAU
#pragma unroll
  for (int e = 0; e < 5; ++e) {
    const int hh = t + e * 256;
    float o = vfr[e];
    if (gate) o = o - tt * uh[(size_t)s * CDIM + hh] + BETAC * tt * ah[(size_t)s * CDIM + hh];
    o += vpr[e];
    const int head = hh >> 6, d = hh & 63;
    vtp[(((size_t)b * NH + head) * DHD + d) * KVP + s] = f2b(o);
  }
}

// ---------------- launch ----------------

extern "C" void kernel_launch(void* const* d_in, const int* in_sizes, int n_in,
                              void* d_out, int out_size, void* d_ws, size_t ws_size,
                              hipStream_t stream) {
  const float* X   = (const float*)d_in[0];
  const float* enc = (const float*)d_in[1];
  const float* Wq  = (const float*)d_in[2];
  const float* Wk  = (const float*)d_in[3];
  const float* Wv  = (const float*)d_in[4];
  const float* Wo  = (const float*)d_in[5];
  const float* bo  = (const float*)d_in[6];
  const float* Bp  = (const float*)d_in[7];
  const float* uh  = (const float*)d_in[8];
  const float* ah  = (const float*)d_in[9];
  float* out = (float*)d_out;

  char* w = (char*)d_ws;
  unsigned short* Xb   = (unsigned short*)(w);                // 8192*1280 bf16
  unsigned short* attn = (unsigned short*)(w + 20971520);     // 8192*1280 bf16 (attn out)
  float*          pk   = (float*)         (w + 20971520);     // alias: 8*256*1280 f32, dead before attn written
  unsigned short* WqT  = (unsigned short*)(w + 41943040);     // 1280*1280 bf16
  unsigned short* WoT  = (unsigned short*)(w + 45219840);     // 1280*1280 bf16
  unsigned short* WkT  = (unsigned short*)(w + 48496640);     // 1280*2048 bf16
  unsigned short* WvT  = (unsigned short*)(w + 53739520);     // 1280*2048 bf16
  unsigned short* encb = (unsigned short*)(w + 58982400);     // 256*2048 bf16
  unsigned short* kp   = (unsigned short*)(w + 61997056);     // 2*20*96*64 bf16
  unsigned short* vtp  = (unsigned short*)(w + 62488576);     // 2*20*64*96 bf16
  // total 62,980,096 B

  prep_trans_kernel<<<2592, 256, 0, stream>>>(enc, encb,
      Wq, WqT, Wo, WoT, Wk, WkT, Wv, WvT);

  gemm_kv_xconv<<<2208, 256, 0, stream>>>(encb, WkT, WvT, pk, X, Xb);
  cora_kernel<<<BATCH * KVP, 256, 0, stream>>>(pk, Bp, uh, ah, vtp, kp);

  gemm_q_attn<<<640, 256, 0, stream>>>(Xb, WqT, kp, vtp, attn);
  gemm_bt<<<640, 256, 0, stream>>>(attn, WoT, out, bo, BATCH * SQL, CDIM, CDIM);
}